// Round 11
// baseline (39.651 us; speedup 1.0000x reference)
//
#include <hip/hip_runtime.h>
#include <hip/hip_bf16.h>

// GNN layer: out = (A @ x) @ W^T + bias,  A = fixed 8-neighbor stencil.
// x[64][65536] f32, W[256][65536] f32, bias[256], out[64][256] f32.
// R11: fused stencil+gemm (h1 in LDS only) with explicit W register
// prefetch (16 float4/wave in flight); 512 blocks x 512 thr, 2 blocks/CU;
// bf16 partials [512][n][m]; deterministic reduce.

#define MB    64
#define NOUT  256
#define KDIM  65536
#define NTOT  (MB * KDIM)
#define KSP   128               // k-span per block
#define NCH   (KDIM / KSP)      // 512 blocks
#define OTOT  (MB * NOUT)       // 16384
#define LSTR  136               // LDS row stride (ushorts); 68 dwords = 4 mod 32

typedef __attribute__((ext_vector_type(8))) short bf16x8;
typedef __attribute__((ext_vector_type(8))) unsigned short ushort8v;
typedef __attribute__((ext_vector_type(4))) float f32x4;

__device__ __forceinline__ ushort f2bf(float f) {
    __hip_bfloat16 h = __float2bfloat16(f);
    return *reinterpret_cast<ushort*>(&h);
}
__device__ __forceinline__ float bf2f(ushort u) {
    return __uint_as_float((unsigned)u << 16);
}

// ---------------------------------------------------------------------------
// Stencil: 8 bf16 h1 values at flat index g.  h1[b,i] = x[b,i] +
// sum_o ([center(i)]+[center(i+o)])*x[b,i+o]; centers = flat 257..65278
// (matches reference COO). Clamped OOB loads only feed weight-0 terms.
// ---------------------------------------------------------------------------
__device__ __forceinline__ ushort8v stencil8v(const float* __restrict__ x, int g) {
    const int i8 = g & (KDIM - 1);
    union Span { float4 v[4]; float f[16]; };
    Span u, c, d;
    #pragma unroll
    for (int q = 0; q < 4; ++q) {
        int bu = g - 260 + 4 * q; if (bu < 0) bu = 0;
        int bc = g - 4   + 4 * q; if (bc < 0) bc = 0; if (bc > NTOT - 4) bc = NTOT - 4;
        int bd = g + 252 + 4 * q; if (bd > NTOT - 4) bd = NTOT - 4;
        u.v[q] = *(const float4*)(x + bu);
        c.v[q] = *(const float4*)(x + bc);
        d.v[q] = *(const float4*)(x + bd);
    }
    ushort8v ov;
    if (i8 >= 520 && i8 <= 65008) {          // fast path: everything interior
        #pragma unroll
        for (int e = 0; e < 8; ++e) {
            float nb = c.f[3 + e] + c.f[5 + e]
                     + u.f[3 + e] + u.f[4 + e] + u.f[5 + e]
                     + d.f[3 + e] + d.f[4 + e] + d.f[5 + e];
            ov[e] = (short)f2bf(fmaf(2.0f, nb, c.f[4 + e]));
        }
    } else {
        #pragma unroll
        for (int e = 0; e < 8; ++e) {
            const int ii = i8 + e;
            const float ci = ((unsigned)(ii - 257) <= (65278u - 257u)) ? 1.0f : 0.0f;
            float s = c.f[4 + e];
            const int   doff[8] = {-1, 1, -257, -256, -255, 255, 256, 257};
            const float* src[8] = {&c.f[3 + e], &c.f[5 + e],
                                   &u.f[3 + e], &u.f[4 + e], &u.f[5 + e],
                                   &d.f[3 + e], &d.f[4 + e], &d.f[5 + e]};
            #pragma unroll
            for (int t = 0; t < 8; ++t) {
                const int j = ii + doff[t];
                const float cj = ((unsigned)(j - 257) <= (65278u - 257u)) ? 1.0f : 0.0f;
                s = fmaf(ci + cj, *src[t], s);
            }
            ov[e] = (short)f2bf(s);
        }
    }
    return ov;
}

// ---------------------------------------------------------------------------
// FUSED kernel. Block = k-chunk kp (512 blocks, 2/CU). 512 threads.
// Phase A: h1 slice [64 m][128 k] -> LDS bf16, stride 136 (2-way banks).
// Phase B: 8 waves; wave owns n-tiles {2w, 2w+1}; ALL W for the span
//          prefetched into wreg[16] (64 VGPR) before compute; A-frags
//          shared between the two n-halves. bf16 partial [kp][n][m].
// XCD-chunk: kp = (b%8)*64 + b/8 -> contiguous kp per XCD share x halo in L2.
// ---------------------------------------------------------------------------
__global__ __launch_bounds__(512, 4) void fused_sg(const float* __restrict__ x,
                                                   const float* __restrict__ W,
                                                   ushort* __restrict__ part) {
    __shared__ ushort hs[MB * LSTR];     // 17408 B
    const int b  = blockIdx.x;
    const int kp = (b & 7) * 64 + (b >> 3);      // 0..511
    const int t  = threadIdx.x;

    // ---- Phase A: stencil -> LDS ----
    {
        const int m = t >> 3;                    // 0..63
        const int j = t & 7;                     // k-offset j*16
        const int g = m * KDIM + kp * KSP + j * 16;
        ushort8v o0 = stencil8v(x, g);
        ushort8v o1 = stencil8v(x, g + 8);
        *(ushort8v*)&hs[m * LSTR + j * 16]     = o0;
        *(ushort8v*)&hs[m * LSTR + j * 16 + 8] = o1;
    }
    __syncthreads();

    // ---- Phase B: MFMA gemm, deep W prefetch ----
    const int wid = t >> 6;                      // 0..7
    const int l   = t & 63;
    const int lr  = l & 15;
    const int lg  = l >> 4;
    const int nt0 = wid * 2;

    const float* wp0 = W + (size_t)(nt0 * 16 + lr) * KDIM + kp * KSP + lg * 8;
    const float* wp1 = wp0 + (size_t)16 * KDIM;

    float4 wr0[8], wr1[8];
    #pragma unroll
    for (int q = 0; q < 4; ++q) {
        wr0[2 * q]     = *(const float4*)(wp0 + q * 32);
        wr0[2 * q + 1] = *(const float4*)(wp0 + q * 32 + 4);
        wr1[2 * q]     = *(const float4*)(wp1 + q * 32);
        wr1[2 * q + 1] = *(const float4*)(wp1 + q * 32 + 4);
    }

    f32x4 acc0[4], acc1[4];
    #pragma unroll
    for (int a = 0; a < 4; ++a) {
        acc0[a] = (f32x4){0.f, 0.f, 0.f, 0.f};
        acc1[a] = (f32x4){0.f, 0.f, 0.f, 0.f};
    }

    #pragma unroll
    for (int ks = 0; ks < KSP / 32; ++ks) {      // 4 fully-unrolled steps
        bf16x8 af[4];
        #pragma unroll
        for (int mt = 0; mt < 4; ++mt)
            af[mt] = *(const bf16x8*)&hs[(mt * 16 + lr) * LSTR + lg * 8 + ks * 32];
        union { ushort u[8]; bf16x8 v; } b0, b1;
        #pragma unroll
        for (int e = 0; e < 4; ++e) {
            b0.u[e]     = f2bf(wr0[2 * ks][e]);
            b0.u[4 + e] = f2bf(wr0[2 * ks + 1][e]);
            b1.u[e]     = f2bf(wr1[2 * ks][e]);
            b1.u[4 + e] = f2bf(wr1[2 * ks + 1][e]);
        }
        #pragma unroll
        for (int mt = 0; mt < 4; ++mt)
            acc0[mt] = __builtin_amdgcn_mfma_f32_16x16x32_bf16(af[mt], b0.v,
                                                               acc0[mt], 0, 0, 0);
        #pragma unroll
        for (int mt = 0; mt < 4; ++mt)
            acc1[mt] = __builtin_amdgcn_mfma_f32_16x16x32_bf16(af[mt], b1.v,
                                                               acc1[mt], 0, 0, 0);
    }

    // D layout: n-col = lane&15, m = (lane>>4)*4 + reg (m89/m91-verified).
    // part[kp][n][m]: lane's 4 m consecutive -> ushort4 stores.
    ushort* pb0 = part + (size_t)kp * OTOT + (size_t)(nt0 * 16 + lr) * MB;
    ushort* pb1 = pb0 + (size_t)16 * MB;
    #pragma unroll
    for (int mt = 0; mt < 4; ++mt) {
        ushort4 s0, s1;
        s0.x = f2bf(acc0[mt][0]); s0.y = f2bf(acc0[mt][1]);
        s0.z = f2bf(acc0[mt][2]); s0.w = f2bf(acc0[mt][3]);
        s1.x = f2bf(acc1[mt][0]); s1.y = f2bf(acc1[mt][1]);
        s1.z = f2bf(acc1[mt][2]); s1.w = f2bf(acc1[mt][3]);
        *(ushort4*)(pb0 + mt * 16 + lg * 4) = s0;
        *(ushort4*)(pb1 + mt * 16 + lg * 4) = s1;
    }
}

// ---------------------------------------------------------------------------
// Reduce 512 bf16 partials (+bias) -> f32 out[64][256].
// 512 blocks x 256 thr: 8 threads/output, 64 chunks each, LDS combine.
// part[kc][n*64+m]; out[m][n].
// ---------------------------------------------------------------------------
__global__ __launch_bounds__(256) void reduce_bf16(const ushort* __restrict__ part,
                                                   const float* __restrict__ bias,
                                                   float* __restrict__ out) {
    __shared__ float red[256];
    const int ol = threadIdx.x & 31;
    const int cg = threadIdx.x >> 5;             // 0..7 -> 64 chunks each
    const int o  = blockIdx.x * 32 + ol;         // 0..16383
    const ushort* p = part + (size_t)cg * 64 * OTOT + o;
    float s0 = 0.f, s1 = 0.f, s2 = 0.f, s3 = 0.f;
    #pragma unroll 4
    for (int i = 0; i < 64; i += 4) {
        s0 += bf2f(p[(size_t)(i + 0) * OTOT]);
        s1 += bf2f(p[(size_t)(i + 1) * OTOT]);
        s2 += bf2f(p[(size_t)(i + 2) * OTOT]);
        s3 += bf2f(p[(size_t)(i + 3) * OTOT]);
    }
    red[threadIdx.x] = (s0 + s1) + (s2 + s3);
    __syncthreads();
    if (cg == 0) {
        float v = red[ol];
        #pragma unroll
        for (int jj = 1; jj < 8; ++jj) v += red[jj * 32 + ol];
        const int n = o >> 6, m = o & 63;
        out[m * NOUT + n] = v + bias[n];
    }
}

// ---------------------------------------------------------------------------
extern "C" void kernel_launch(void* const* d_in, const int* in_sizes, int n_in,
                              void* d_out, int out_size, void* d_ws, size_t ws_size,
                              hipStream_t stream) {
    const float* x    = (const float*)d_in[0];
    const float* W    = (const float*)d_in[1];
    const float* bias = (const float*)d_in[2];
    float* out = (float*)d_out;

    ushort* part = (ushort*)d_ws;                // 512*16384*2 = 16 MiB

    fused_sg<<<NCH, 512, 0, stream>>>(x, W, part);
    reduce_bf16<<<OTOT / 32, 256, 0, stream>>>(part, bias, out);
}

// Round 12
// 34.365 us; speedup vs baseline: 1.1538x; 1.1538x over previous
//
#include <hip/hip_runtime.h>
#include <hip/hip_bf16.h>

// GNN layer: out = (A @ x) @ W^T + bias,  A = fixed 8-neighbor stencil.
// x[64][65536] f32, W[256][65536] f32, bias[256], out[64][256] f32.
// R12: R10 fused structure (h1 in LDS only) + W loads pinned with inline-asm
// global_load_dwordx4 (16 in flight per wave across the barrier).

#define MB    64
#define NOUT  256
#define KDIM  65536
#define NTOT  (MB * KDIM)
#define KSP   256               // k-span per block
#define NCH   (KDIM / KSP)      // 256 blocks
#define OTOT  (MB * NOUT)       // 16384
#define LSTR  272               // LDS row stride in ushorts (544 B)

typedef __attribute__((ext_vector_type(8))) short bf16x8;
typedef __attribute__((ext_vector_type(8))) unsigned short ushort8v;
typedef __attribute__((ext_vector_type(4))) float f32x4;

__device__ __forceinline__ ushort f2bf(float f) {
    __hip_bfloat16 h = __float2bfloat16(f);
    return *reinterpret_cast<ushort*>(&h);
}
__device__ __forceinline__ float bf2f(ushort u) {
    return __uint_as_float((unsigned)u << 16);
}

// ---------------------------------------------------------------------------
// Stencil: 8 bf16 h1 values at flat index g.  h1[b,i] = x[b,i] +
// sum_o ([center(i)]+[center(i+o)])*x[b,i+o]; centers = flat 257..65278
// (matches reference COO). Clamped OOB loads only feed weight-0 terms.
// ---------------------------------------------------------------------------
__device__ __forceinline__ ushort8v stencil8v(const float* __restrict__ x, int g) {
    const int i8 = g & (KDIM - 1);
    union Span { float4 v[4]; float f[16]; };
    Span u, c, d;
    #pragma unroll
    for (int q = 0; q < 4; ++q) {
        int bu = g - 260 + 4 * q; if (bu < 0) bu = 0;
        int bc = g - 4   + 4 * q; if (bc < 0) bc = 0; if (bc > NTOT - 4) bc = NTOT - 4;
        int bd = g + 252 + 4 * q; if (bd > NTOT - 4) bd = NTOT - 4;
        u.v[q] = *(const float4*)(x + bu);
        c.v[q] = *(const float4*)(x + bc);
        d.v[q] = *(const float4*)(x + bd);
    }
    ushort8v ov;
    if (i8 >= 520 && i8 <= 65008) {          // fast path: everything interior
        #pragma unroll
        for (int e = 0; e < 8; ++e) {
            float nb = c.f[3 + e] + c.f[5 + e]
                     + u.f[3 + e] + u.f[4 + e] + u.f[5 + e]
                     + d.f[3 + e] + d.f[4 + e] + d.f[5 + e];
            ov[e] = (short)f2bf(fmaf(2.0f, nb, c.f[4 + e]));
        }
    } else {
        #pragma unroll
        for (int e = 0; e < 8; ++e) {
            const int ii = i8 + e;
            const float ci = ((unsigned)(ii - 257) <= (65278u - 257u)) ? 1.0f : 0.0f;
            float s = c.f[4 + e];
            const int   doff[8] = {-1, 1, -257, -256, -255, 255, 256, 257};
            const float* src[8] = {&c.f[3 + e], &c.f[5 + e],
                                   &u.f[3 + e], &u.f[4 + e], &u.f[5 + e],
                                   &d.f[3 + e], &d.f[4 + e], &d.f[5 + e]};
            #pragma unroll
            for (int t = 0; t < 8; ++t) {
                const int j = ii + doff[t];
                const float cj = ((unsigned)(j - 257) <= (65278u - 257u)) ? 1.0f : 0.0f;
                s = fmaf(ci + cj, *src[t], s);
            }
            ov[e] = (short)f2bf(s);
        }
    }
    return ov;
}

#define GL4(dst, base, OFFSTR) \
    asm volatile("global_load_dwordx4 %0, %1, off" OFFSTR : "=v"(dst) : "v"(base))

// ---------------------------------------------------------------------------
// FUSED kernel. Block = k-chunk kp (256 blocks). 1024 threads, 16 waves.
// Phase A: h1 slice [64 m][256 k] -> LDS bf16 (stride 272).
// Phase B: wave = n-tile nt; 16 asm-pinned W loads (whole k-span) in flight
//          across the barrier; convert f32->bf16; 8 k-steps x 4 m-tiles MFMA.
// bf16 partial [kp][n][m]. XCD-chunk: kp = (b%8)*32 + b/8.
// ---------------------------------------------------------------------------
__global__ __launch_bounds__(1024, 4) void fused_sg(const float* __restrict__ x,
                                                    const float* __restrict__ W,
                                                    ushort* __restrict__ part) {
    __shared__ ushort hs[MB * LSTR];     // 34816 B
    const int b  = blockIdx.x;
    const int kp = (b & 7) * 32 + (b >> 3);      // 0..255
    const int t  = threadIdx.x;

    // ---- Phase A: stencil (16 elems/thread) ----
    const int m = t >> 4;                        // 0..63
    const int j = t & 15;                        // k-offset j*16
    const int g = m * KDIM + kp * KSP + j * 16;
    ushort8v o0 = stencil8v(x, g);
    ushort8v o1 = stencil8v(x, g + 8);

    // ---- Phase B addresses + pinned W loads (issued before barrier) ----
    const int nt = t >> 6;                       // 0..15 n-tile
    const int l  = t & 63;
    const int lr = l & 15;
    const int lg = l >> 4;
    const float* wbase = W + (size_t)(nt * 16 + lr) * KDIM + kp * KSP + lg * 8;

    float4 wv0, wv1, wv2, wv3, wv4, wv5, wv6, wv7;
    float4 wv8, wv9, wv10, wv11, wv12, wv13, wv14, wv15;
    GL4(wv0,  wbase, "");
    GL4(wv1,  wbase, " offset:16");
    GL4(wv2,  wbase, " offset:128");
    GL4(wv3,  wbase, " offset:144");
    GL4(wv4,  wbase, " offset:256");
    GL4(wv5,  wbase, " offset:272");
    GL4(wv6,  wbase, " offset:384");
    GL4(wv7,  wbase, " offset:400");
    GL4(wv8,  wbase, " offset:512");
    GL4(wv9,  wbase, " offset:528");
    GL4(wv10, wbase, " offset:640");
    GL4(wv11, wbase, " offset:656");
    GL4(wv12, wbase, " offset:768");
    GL4(wv13, wbase, " offset:784");
    GL4(wv14, wbase, " offset:896");
    GL4(wv15, wbase, " offset:912");

    // ---- stencil -> LDS, barrier ----
    *(ushort8v*)&hs[m * LSTR + j * 16]     = o0;
    *(ushort8v*)&hs[m * LSTR + j * 16 + 8] = o1;
    __syncthreads();
    // All asm W loads are untracked by the compiler: wait explicitly, and
    // fence the scheduler so converts can't hoist above the wait (rule #18).
    asm volatile("s_waitcnt vmcnt(0)" ::: "memory");
    __builtin_amdgcn_sched_barrier(0);

    // ---- MFMA over 8 k-steps x 4 m-tiles ----
    f32x4 acc0 = (f32x4){0.f,0.f,0.f,0.f}, acc1 = (f32x4){0.f,0.f,0.f,0.f};
    f32x4 acc2 = (f32x4){0.f,0.f,0.f,0.f}, acc3 = (f32x4){0.f,0.f,0.f,0.f};

#define STEP(KS, WA, WB)                                                       \
    {                                                                          \
        union { ushort u[8]; bf16x8 v; } bb;                                   \
        bb.u[0] = f2bf(WA.x); bb.u[1] = f2bf(WA.y);                            \
        bb.u[2] = f2bf(WA.z); bb.u[3] = f2bf(WA.w);                            \
        bb.u[4] = f2bf(WB.x); bb.u[5] = f2bf(WB.y);                            \
        bb.u[6] = f2bf(WB.z); bb.u[7] = f2bf(WB.w);                            \
        bf16x8 af0 = *(const bf16x8*)&hs[(0 * 16 + lr) * LSTR + lg * 8 + KS * 32]; \
        bf16x8 af1 = *(const bf16x8*)&hs[(1 * 16 + lr) * LSTR + lg * 8 + KS * 32]; \
        bf16x8 af2 = *(const bf16x8*)&hs[(2 * 16 + lr) * LSTR + lg * 8 + KS * 32]; \
        bf16x8 af3 = *(const bf16x8*)&hs[(3 * 16 + lr) * LSTR + lg * 8 + KS * 32]; \
        acc0 = __builtin_amdgcn_mfma_f32_16x16x32_bf16(af0, bb.v, acc0, 0, 0, 0); \
        acc1 = __builtin_amdgcn_mfma_f32_16x16x32_bf16(af1, bb.v, acc1, 0, 0, 0); \
        acc2 = __builtin_amdgcn_mfma_f32_16x16x32_bf16(af2, bb.v, acc2, 0, 0, 0); \
        acc3 = __builtin_amdgcn_mfma_f32_16x16x32_bf16(af3, bb.v, acc3, 0, 0, 0); \
    }

    STEP(0, wv0,  wv1)
    STEP(1, wv2,  wv3)
    STEP(2, wv4,  wv5)
    STEP(3, wv6,  wv7)
    STEP(4, wv8,  wv9)
    STEP(5, wv10, wv11)
    STEP(6, wv12, wv13)
    STEP(7, wv14, wv15)
#undef STEP

    // D layout: n-col = lane&15, m = (lane>>4)*4 + reg (m89/m91-verified).
    // part[kp][n][m]: lane's 4 m consecutive -> ushort4 stores.
    ushort* pb = part + (size_t)kp * OTOT + (size_t)(nt * 16 + lr) * MB;
    ushort4 s;
    s.x = f2bf(acc0[0]); s.y = f2bf(acc0[1]); s.z = f2bf(acc0[2]); s.w = f2bf(acc0[3]);
    *(ushort4*)(pb + 0 * 16 + lg * 4) = s;
    s.x = f2bf(acc1[0]); s.y = f2bf(acc1[1]); s.z = f2bf(acc1[2]); s.w = f2bf(acc1[3]);
    *(ushort4*)(pb + 1 * 16 + lg * 4) = s;
    s.x = f2bf(acc2[0]); s.y = f2bf(acc2[1]); s.z = f2bf(acc2[2]); s.w = f2bf(acc2[3]);
    *(ushort4*)(pb + 2 * 16 + lg * 4) = s;
    s.x = f2bf(acc3[0]); s.y = f2bf(acc3[1]); s.z = f2bf(acc3[2]); s.w = f2bf(acc3[3]);
    *(ushort4*)(pb + 3 * 16 + lg * 4) = s;
}

// ---------------------------------------------------------------------------
// Reduce 256 bf16 partials (+bias) -> f32 out[64][256].
// 512 blocks x 256 thr: 8 threads/output, 32 chunks each, LDS combine.
// part[kc][n*64+m]; out[m][n].
// ---------------------------------------------------------------------------
__global__ __launch_bounds__(256) void reduce_bf16(const ushort* __restrict__ part,
                                                   const float* __restrict__ bias,
                                                   float* __restrict__ out) {
    __shared__ float red[256];
    const int ol = threadIdx.x & 31;
    const int cg = threadIdx.x >> 5;             // 0..7 -> 32 chunks each
    const int o  = blockIdx.x * 32 + ol;         // 0..16383
    const ushort* p = part + (size_t)cg * 32 * OTOT + o;
    float s0 = 0.f, s1 = 0.f, s2 = 0.f, s3 = 0.f;
    #pragma unroll 2
    for (int i = 0; i < 32; i += 4) {
        s0 += bf2f(p[(size_t)(i + 0) * OTOT]);
        s1 += bf2f(p[(size_t)(i + 1) * OTOT]);
        s2 += bf2f(p[(size_t)(i + 2) * OTOT]);
        s3 += bf2f(p[(size_t)(i + 3) * OTOT]);
    }
    red[threadIdx.x] = (s0 + s1) + (s2 + s3);
    __syncthreads();
    if (cg == 0) {
        float v = red[ol];
        #pragma unroll
        for (int jj = 1; jj < 8; ++jj) v += red[jj * 32 + ol];
        const int n = o >> 6, m = o & 63;
        out[m * NOUT + n] = v + bias[n];
    }
}

// ---------------------------------------------------------------------------
extern "C" void kernel_launch(void* const* d_in, const int* in_sizes, int n_in,
                              void* d_out, int out_size, void* d_ws, size_t ws_size,
                              hipStream_t stream) {
    const float* x    = (const float*)d_in[0];
    const float* W    = (const float*)d_in[1];
    const float* bias = (const float*)d_in[2];
    float* out = (float*)d_out;

    ushort* part = (ushort*)d_ws;                // 256*16384*2 = 8 MiB

    fused_sg<<<NCH, 1024, 0, stream>>>(x, W, part);
    reduce_bf16<<<OTOT / 32, 256, 0, stream>>>(part, bias, out);
}

// Round 13
// 34.076 us; speedup vs baseline: 1.1636x; 1.0085x over previous
//
#include <hip/hip_runtime.h>
#include <hip/hip_bf16.h>

// GNN layer: out = (A @ x) @ W^T + bias,  A = fixed 8-neighbor stencil.
// x[64][65536] f32, W[256][65536] f32, bias[256], out[64][256] f32.
// R13: R12 fused structure, but W loads issued CONCURRENTLY with the stencil
// x-loads (8 before / 8 after stencil math, FIFO vmcnt drains both together)
// so the block pays one memory latency instead of two.

#define MB    64
#define NOUT  256
#define KDIM  65536
#define NTOT  (MB * KDIM)
#define KSP   256               // k-span per block
#define NCH   (KDIM / KSP)      // 256 blocks
#define OTOT  (MB * NOUT)       // 16384
#define LSTR  272               // LDS row stride in ushorts (544 B)

typedef __attribute__((ext_vector_type(8))) short bf16x8;
typedef __attribute__((ext_vector_type(8))) unsigned short ushort8v;
typedef __attribute__((ext_vector_type(4))) float f32x4;

__device__ __forceinline__ ushort f2bf(float f) {
    __hip_bfloat16 h = __float2bfloat16(f);
    return *reinterpret_cast<ushort*>(&h);
}
__device__ __forceinline__ float bf2f(ushort u) {
    return __uint_as_float((unsigned)u << 16);
}

// ---------------------------------------------------------------------------
// Stencil: 8 bf16 h1 values at flat index g.  h1[b,i] = x[b,i] +
// sum_o ([center(i)]+[center(i+o)])*x[b,i+o]; centers = flat 257..65278
// (matches reference COO). Clamped OOB loads only feed weight-0 terms.
// ---------------------------------------------------------------------------
__device__ __forceinline__ ushort8v stencil8v(const float* __restrict__ x, int g) {
    const int i8 = g & (KDIM - 1);
    union Span { float4 v[4]; float f[16]; };
    Span u, c, d;
    #pragma unroll
    for (int q = 0; q < 4; ++q) {
        int bu = g - 260 + 4 * q; if (bu < 0) bu = 0;
        int bc = g - 4   + 4 * q; if (bc < 0) bc = 0; if (bc > NTOT - 4) bc = NTOT - 4;
        int bd = g + 252 + 4 * q; if (bd > NTOT - 4) bd = NTOT - 4;
        u.v[q] = *(const float4*)(x + bu);
        c.v[q] = *(const float4*)(x + bc);
        d.v[q] = *(const float4*)(x + bd);
    }
    ushort8v ov;
    if (i8 >= 520 && i8 <= 65008) {          // fast path: everything interior
        #pragma unroll
        for (int e = 0; e < 8; ++e) {
            float nb = c.f[3 + e] + c.f[5 + e]
                     + u.f[3 + e] + u.f[4 + e] + u.f[5 + e]
                     + d.f[3 + e] + d.f[4 + e] + d.f[5 + e];
            ov[e] = (short)f2bf(fmaf(2.0f, nb, c.f[4 + e]));
        }
    } else {
        #pragma unroll
        for (int e = 0; e < 8; ++e) {
            const int ii = i8 + e;
            const float ci = ((unsigned)(ii - 257) <= (65278u - 257u)) ? 1.0f : 0.0f;
            float s = c.f[4 + e];
            const int   doff[8] = {-1, 1, -257, -256, -255, 255, 256, 257};
            const float* src[8] = {&c.f[3 + e], &c.f[5 + e],
                                   &u.f[3 + e], &u.f[4 + e], &u.f[5 + e],
                                   &d.f[3 + e], &d.f[4 + e], &d.f[5 + e]};
            #pragma unroll
            for (int t = 0; t < 8; ++t) {
                const int j = ii + doff[t];
                const float cj = ((unsigned)(j - 257) <= (65278u - 257u)) ? 1.0f : 0.0f;
                s = fmaf(ci + cj, *src[t], s);
            }
            ov[e] = (short)f2bf(s);
        }
    }
    return ov;
}

#define GL4(dst, base, OFFSTR) \
    asm volatile("global_load_dwordx4 %0, %1, off" OFFSTR : "=v"(dst) : "v"(base))

// ---------------------------------------------------------------------------
// FUSED kernel. Block = k-chunk kp (256 blocks). 1024 threads, 16 waves.
// Order per wave: issue 8 W loads -> stencil (x loads overlap W in flight;
// FIFO vmcnt drains both) -> issue remaining 8 W loads -> LDS write ->
// barrier -> vmcnt(0) (cheap: mostly drained) -> 8 k-steps x 4 m-tiles MFMA.
// bf16 partial [kp][n][m]. XCD-chunk: kp = (b%8)*32 + b/8.
// ---------------------------------------------------------------------------
__global__ __launch_bounds__(1024, 4) void fused_sg(const float* __restrict__ x,
                                                    const float* __restrict__ W,
                                                    ushort* __restrict__ part) {
    __shared__ ushort hs[MB * LSTR];     // 34816 B
    const int b  = blockIdx.x;
    const int kp = (b & 7) * 32 + (b >> 3);      // 0..255
    const int t  = threadIdx.x;

    // ---- addresses ----
    const int m = t >> 4;                        // 0..63   (phase A role)
    const int j = t & 15;                        // k-offset j*16
    const int g = m * KDIM + kp * KSP + j * 16;
    const int nt = t >> 6;                       // 0..15   (phase B role)
    const int l  = t & 63;
    const int lr = l & 15;
    const int lg = l >> 4;
    const float* wbase = W + (size_t)(nt * 16 + lr) * KDIM + kp * KSP + lg * 8;

    // ---- first half of W loads: in flight during the whole stencil ----
    float4 wv0, wv1, wv2, wv3, wv4, wv5, wv6, wv7;
    float4 wv8, wv9, wv10, wv11, wv12, wv13, wv14, wv15;
    GL4(wv0,  wbase, "");
    GL4(wv1,  wbase, " offset:16");
    GL4(wv2,  wbase, " offset:128");
    GL4(wv3,  wbase, " offset:144");
    GL4(wv4,  wbase, " offset:256");
    GL4(wv5,  wbase, " offset:272");
    GL4(wv6,  wbase, " offset:384");
    GL4(wv7,  wbase, " offset:400");

    // ---- stencil (x loads overlap the W stream) ----
    ushort8v o0 = stencil8v(x, g);
    ushort8v o1 = stencil8v(x, g + 8);

    // ---- second half of W loads (stencil registers now dead) ----
    GL4(wv8,  wbase, " offset:512");
    GL4(wv9,  wbase, " offset:528");
    GL4(wv10, wbase, " offset:640");
    GL4(wv11, wbase, " offset:656");
    GL4(wv12, wbase, " offset:768");
    GL4(wv13, wbase, " offset:784");
    GL4(wv14, wbase, " offset:896");
    GL4(wv15, wbase, " offset:912");

    // ---- stencil -> LDS, barrier ----
    *(ushort8v*)&hs[m * LSTR + j * 16]     = o0;
    *(ushort8v*)&hs[m * LSTR + j * 16 + 8] = o1;
    __syncthreads();
    // Asm W loads are untracked by the compiler: wait explicitly, and fence
    // the scheduler so converts can't hoist above the wait (rule #18).
    asm volatile("s_waitcnt vmcnt(0)" ::: "memory");
    __builtin_amdgcn_sched_barrier(0);

    // ---- MFMA over 8 k-steps x 4 m-tiles ----
    f32x4 acc0 = (f32x4){0.f,0.f,0.f,0.f}, acc1 = (f32x4){0.f,0.f,0.f,0.f};
    f32x4 acc2 = (f32x4){0.f,0.f,0.f,0.f}, acc3 = (f32x4){0.f,0.f,0.f,0.f};

#define STEP(KS, WA, WB)                                                       \
    {                                                                          \
        union { ushort u[8]; bf16x8 v; } bb;                                   \
        bb.u[0] = f2bf(WA.x); bb.u[1] = f2bf(WA.y);                            \
        bb.u[2] = f2bf(WA.z); bb.u[3] = f2bf(WA.w);                            \
        bb.u[4] = f2bf(WB.x); bb.u[5] = f2bf(WB.y);                            \
        bb.u[6] = f2bf(WB.z); bb.u[7] = f2bf(WB.w);                            \
        bf16x8 af0 = *(const bf16x8*)&hs[(0 * 16 + lr) * LSTR + lg * 8 + KS * 32]; \
        bf16x8 af1 = *(const bf16x8*)&hs[(1 * 16 + lr) * LSTR + lg * 8 + KS * 32]; \
        bf16x8 af2 = *(const bf16x8*)&hs[(2 * 16 + lr) * LSTR + lg * 8 + KS * 32]; \
        bf16x8 af3 = *(const bf16x8*)&hs[(3 * 16 + lr) * LSTR + lg * 8 + KS * 32]; \
        acc0 = __builtin_amdgcn_mfma_f32_16x16x32_bf16(af0, bb.v, acc0, 0, 0, 0); \
        acc1 = __builtin_amdgcn_mfma_f32_16x16x32_bf16(af1, bb.v, acc1, 0, 0, 0); \
        acc2 = __builtin_amdgcn_mfma_f32_16x16x32_bf16(af2, bb.v, acc2, 0, 0, 0); \
        acc3 = __builtin_amdgcn_mfma_f32_16x16x32_bf16(af3, bb.v, acc3, 0, 0, 0); \
    }

    STEP(0, wv0,  wv1)
    STEP(1, wv2,  wv3)
    STEP(2, wv4,  wv5)
    STEP(3, wv6,  wv7)
    STEP(4, wv8,  wv9)
    STEP(5, wv10, wv11)
    STEP(6, wv12, wv13)
    STEP(7, wv14, wv15)
#undef STEP

    // D layout: n-col = lane&15, m = (lane>>4)*4 + reg (m89/m91-verified).
    // part[kp][n][m]: lane's 4 m consecutive -> ushort4 stores.
    ushort* pb = part + (size_t)kp * OTOT + (size_t)(nt * 16 + lr) * MB;
    ushort4 s;
    s.x = f2bf(acc0[0]); s.y = f2bf(acc0[1]); s.z = f2bf(acc0[2]); s.w = f2bf(acc0[3]);
    *(ushort4*)(pb + 0 * 16 + lg * 4) = s;
    s.x = f2bf(acc1[0]); s.y = f2bf(acc1[1]); s.z = f2bf(acc1[2]); s.w = f2bf(acc1[3]);
    *(ushort4*)(pb + 1 * 16 + lg * 4) = s;
    s.x = f2bf(acc2[0]); s.y = f2bf(acc2[1]); s.z = f2bf(acc2[2]); s.w = f2bf(acc2[3]);
    *(ushort4*)(pb + 2 * 16 + lg * 4) = s;
    s.x = f2bf(acc3[0]); s.y = f2bf(acc3[1]); s.z = f2bf(acc3[2]); s.w = f2bf(acc3[3]);
    *(ushort4*)(pb + 3 * 16 + lg * 4) = s;
}

// ---------------------------------------------------------------------------
// Reduce 256 bf16 partials (+bias) -> f32 out[64][256].
// 512 blocks x 256 thr: 8 threads/output, 32 chunks each, LDS combine.
// part[kc][n*64+m]; out[m][n].
// ---------------------------------------------------------------------------
__global__ __launch_bounds__(256) void reduce_bf16(const ushort* __restrict__ part,
                                                   const float* __restrict__ bias,
                                                   float* __restrict__ out) {
    __shared__ float red[256];
    const int ol = threadIdx.x & 31;
    const int cg = threadIdx.x >> 5;             // 0..7 -> 32 chunks each
    const int o  = blockIdx.x * 32 + ol;         // 0..16383
    const ushort* p = part + (size_t)cg * 32 * OTOT + o;
    float s0 = 0.f, s1 = 0.f, s2 = 0.f, s3 = 0.f;
    #pragma unroll 2
    for (int i = 0; i < 32; i += 4) {
        s0 += bf2f(p[(size_t)(i + 0) * OTOT]);
        s1 += bf2f(p[(size_t)(i + 1) * OTOT]);
        s2 += bf2f(p[(size_t)(i + 2) * OTOT]);
        s3 += bf2f(p[(size_t)(i + 3) * OTOT]);
    }
    red[threadIdx.x] = (s0 + s1) + (s2 + s3);
    __syncthreads();
    if (cg == 0) {
        float v = red[ol];
        #pragma unroll
        for (int jj = 1; jj < 8; ++jj) v += red[jj * 32 + ol];
        const int n = o >> 6, m = o & 63;
        out[m * NOUT + n] = v + bias[n];
    }
}

// ---------------------------------------------------------------------------
extern "C" void kernel_launch(void* const* d_in, const int* in_sizes, int n_in,
                              void* d_out, int out_size, void* d_ws, size_t ws_size,
                              hipStream_t stream) {
    const float* x    = (const float*)d_in[0];
    const float* W    = (const float*)d_in[1];
    const float* bias = (const float*)d_in[2];
    float* out = (float*)d_out;

    ushort* part = (ushort*)d_ws;                // 256*16384*2 = 8 MiB

    fused_sg<<<NCH, 1024, 0, stream>>>(x, W, part);
    reduce_bf16<<<OTOT / 32, 256, 0, stream>>>(part, bias, out);
}